// Round 13
// baseline (150.381 us; speedup 1.0000x reference)
//
#include <hip/hip_runtime.h>

// Batched Kalman step: G groups, S=16, M=8, fp32.
// R13 = R12 (quad-per-group, all-register, DPP broadcasts, v2f packed math,
// FT/Q prefetched under the stream-X phase) with the live set pushed under
// the 128-VGPR occupancy boundary (m69: waves/SIMD halve at 64/128/256; R12's
// 136 VGPR -> 2 waves/SIMD; <=128 -> 4 waves/SIMD = 2x latency hiding):
//  - Q prefetch ring 6 -> 2 deep (-16 VGPR): at 4 waves/SIMD TLP replaces
//    prefetch depth
//  - Gauss-Jordan scales the pivot row in-stage -> no pinvD[8] array
// NO launch_bounds min-waves clause (R4/R9: forced VGPR clamp -> GB of spill).

typedef float v2f __attribute__((ext_vector_type(2)));

__device__ __forceinline__ float bq(float x, int t) {
    // broadcast lane t of each quad (DPP quad_perm)
    switch (t & 3) {
    case 0:  return __int_as_float(__builtin_amdgcn_mov_dpp(__float_as_int(x), 0x00, 0xF, 0xF, true));
    case 1:  return __int_as_float(__builtin_amdgcn_mov_dpp(__float_as_int(x), 0x55, 0xF, 0xF, true));
    case 2:  return __int_as_float(__builtin_amdgcn_mov_dpp(__float_as_int(x), 0xAA, 0xF, 0xF, true));
    default: return __int_as_float(__builtin_amdgcn_mov_dpp(__float_as_int(x), 0xFF, 0xF, 0xF, true));
    }
}
__device__ __forceinline__ v2f splat(float c) { v2f r; r.x = c; r.y = c; return r; }

__global__ __launch_bounds__(256) void kalman_kernel(
    const float* __restrict__ g_in,
    const float* __restrict__ g_mean,
    const float* __restrict__ g_cov,
    const float* __restrict__ g_H,
    const float* __restrict__ g_R,
    const float* __restrict__ g_F,
    const float* __restrict__ g_Q,
    float* __restrict__ g_out,
    int G)
{
    const int l = threadIdx.x & 3;                         // lane in quad
    const int g = (blockIdx.x << 6) | (threadIdx.x >> 2);  // group id

    const float* const Pp = g_cov + (size_t)g * 256;
    const float* const Hp = g_H   + (size_t)g * 128;
    const float* const Rp = g_R   + (size_t)g * 64;
    const float* const Fp = g_F   + (size_t)g * 256;
    const float* const Qp = g_Q   + (size_t)g * 256;

    // ---- loads: P col-slab (cols 4l..4l+3 as 2 v2f per row) ----
    v2f Plo[16], Phi[16];
    #pragma unroll
    for (int k = 0; k < 16; ++k) {
        const float4 t = *reinterpret_cast<const float4*>(Pp + k*16 + 4*l);
        Plo[k].x=t.x; Plo[k].y=t.y; Phi[k].x=t.z; Phi[k].y=t.w;
    }
    // HT[k] = {H[2l][k], H[2l+1][k]}
    v2f HT[16];
    {
        float4 ra[4], rb[4];
        #pragma unroll
        for (int p = 0; p < 4; ++p) {
            ra[p] = *reinterpret_cast<const float4*>(Hp + (2*l  )*16 + 4*p);
            rb[p] = *reinterpret_cast<const float4*>(Hp + (2*l+1)*16 + 4*p);
        }
        #pragma unroll
        for (int p = 0; p < 4; ++p) {
            HT[4*p+0].x=ra[p].x; HT[4*p+0].y=rb[p].x;
            HT[4*p+1].x=ra[p].y; HT[4*p+1].y=rb[p].y;
            HT[4*p+2].x=ra[p].z; HT[4*p+2].y=rb[p].z;
            HT[4*p+3].x=ra[p].w; HT[4*p+3].y=rb[p].w;
        }
    }
    // S rows init R (cols 2l, 2l+1)
    v2f S[8];
    #pragma unroll
    for (int i = 0; i < 8; ++i) {
        const float2 t = *reinterpret_cast<const float2*>(Rp + i*8 + 2*l);
        S[i].x=t.x; S[i].y=t.y;
    }
    v2f mnlo, mnhi;
    { const float4 t = *reinterpret_cast<const float4*>(g_mean + (size_t)g*16 + 4*l);
      mnlo.x=t.x; mnlo.y=t.y; mnhi.x=t.z; mnhi.y=t.w; }
    v2f ipv;
    { const float2 t = *reinterpret_cast<const float2*>(g_in + (size_t)g*8 + 2*l);
      ipv.x=t.x; ipv.y=t.y; }

    // ---- CT = H@P (col-slab; H[i][k] = bq(HT[k] comp i&1, i>>1)) ----
    v2f CTlo[8], CThi[8];
    #pragma unroll
    for (int i = 0; i < 8; ++i) {
        v2f alo = {0.f, 0.f}, ahi = {0.f, 0.f};
        #pragma unroll
        for (int k = 0; k < 16; ++k) {
            const float h = bq((i&1) ? HT[k].y : HT[k].x, i>>1);
            alo += splat(h) * Plo[k];
            ahi += splat(h) * Phi[k];
        }
        CTlo[i]=alo; CThi[i]=ahi;
    }

    // ---- S = CT@H^T + R ----
    #pragma unroll
    for (int i = 0; i < 8; ++i) {
        v2f acc = S[i];
        #pragma unroll
        for (int k = 0; k < 16; ++k) {
            const float c = bq((k&2) ? ((k&1)?CThi[i].y:CThi[i].x)
                                     : ((k&1)?CTlo[i].y:CTlo[i].x), k>>2);
            acc += splat(c) * HT[k];
        }
        S[i] = acc;
    }

    // ---- res = inp - H@mean ----
    v2f resd = ipv;
    #pragma unroll
    for (int k = 0; k < 16; ++k) {
        const float m = bq((k&2) ? ((k&1)?mnhi.y:mnhi.x)
                                 : ((k&1)?mnlo.y:mnlo.x), k>>2);
        resd -= splat(m) * HT[k];
    }

    // ---- Gauss-Jordan [S | I] -> Sinv (divergence-free; pivot row scaled
    //      in-stage so no pinvD array) ----
    v2f Ii[8];
    #pragma unroll
    for (int i = 0; i < 8; ++i) {
        Ii[i].x = (2*l   == i) ? 1.f : 0.f;
        Ii[i].y = (2*l+1 == i) ? 1.f : 0.f;
    }
    #pragma unroll
    for (int k = 0; k < 8; ++k) {
        const float pv   = bq((k&1) ? S[k].y : S[k].x, k>>1);
        const float pinv = __builtin_amdgcn_rcpf(pv);
        S[k]  *= splat(pinv);
        Ii[k] *= splat(pinv);
        #pragma unroll
        for (int i = 0; i < 8; ++i) {
            if (i == k) continue;
            const float fi = bq((k&1) ? S[i].y : S[i].x, k>>1);
            S[i]  -= splat(fi) * S[k];
            Ii[i] -= splat(fi) * Ii[k];
        }
    }
    // Ii = Sinv.

    // ==== PREFETCH: FT + 2-row Q ring issued NOW; stream-X hides latency ====
    v2f FTlo[16], FThi[16];
    {
        #pragma unroll
        for (int p = 0; p < 4; ++p) {
            const float4 r0 = *reinterpret_cast<const float4*>(Fp + (4*l+0)*16 + 4*p);
            const float4 r1 = *reinterpret_cast<const float4*>(Fp + (4*l+1)*16 + 4*p);
            const float4 r2 = *reinterpret_cast<const float4*>(Fp + (4*l+2)*16 + 4*p);
            const float4 r3 = *reinterpret_cast<const float4*>(Fp + (4*l+3)*16 + 4*p);
            FTlo[4*p+0].x=r0.x; FTlo[4*p+0].y=r1.x; FThi[4*p+0].x=r2.x; FThi[4*p+0].y=r3.x;
            FTlo[4*p+1].x=r0.y; FTlo[4*p+1].y=r1.y; FThi[4*p+1].x=r2.y; FThi[4*p+1].y=r3.y;
            FTlo[4*p+2].x=r0.z; FTlo[4*p+2].y=r1.z; FThi[4*p+2].x=r2.z; FThi[4*p+2].y=r3.z;
            FTlo[4*p+3].x=r0.w; FTlo[4*p+3].y=r1.w; FThi[4*p+3].x=r2.w; FThi[4*p+3].y=r3.w;
        }
    }
    float4 qbuf[2];
    #pragma unroll
    for (int i = 0; i < 2; ++i)
        qbuf[i] = *reinterpret_cast<const float4*>(Qp + i*16 + 4*l);

    // ---- stream X rows: nm += X[m]*res ; NC(P) -= CT^T[.,m] (x) X[m] ----
    v2f nmL = mnlo, nmH = mnhi;
    #pragma unroll
    for (int m = 0; m < 8; ++m) {
        v2f xlo = {0.f,0.f}, xhi = {0.f,0.f};
        #pragma unroll
        for (int j = 0; j < 8; ++j) {
            const float s = bq((j&1) ? Ii[m].y : Ii[m].x, j>>1);
            xlo += splat(s) * CTlo[j];
            xhi += splat(s) * CThi[j];
        }
        const float r = bq((m&1) ? resd.y : resd.x, m>>1);
        nmL += splat(r) * xlo;
        nmH += splat(r) * xhi;
        #pragma unroll
        for (int s2 = 0; s2 < 16; ++s2) {
            const float c = bq((s2&2) ? ((s2&1)?CThi[m].y:CThi[m].x)
                                      : ((s2&1)?CTlo[m].y:CTlo[m].x), s2>>2);
            Plo[s2] -= splat(c) * xlo;
            Phi[s2] -= splat(c) * xhi;
        }
    }
    // P now holds NC. CT/S/Ii/HT/resd dead.

    // ---- pred_mean = F @ nm -> coalesced float4 ----
    {
        v2f plo = {0.f,0.f}, phi = {0.f,0.f};
        #pragma unroll
        for (int k = 0; k < 16; ++k) {
            const float m = bq((k&2) ? ((k&1)?nmH.y:nmH.x)
                                     : ((k&1)?nmL.y:nmL.x), k>>2);
            plo += splat(m) * FTlo[k];
            phi += splat(m) * FThi[k];
        }
        *reinterpret_cast<float4*>(g_out + (size_t)g*16 + 4*l) =
            make_float4(plo.x, plo.y, phi.x, phi.y);
    }

    // ---- pred_cov rows, fused W=F@NC then out=W@F^T+Q
    //      (2-deep rolling Q ring; all indices compile-time) ----
    float* const out_pc = g_out + (size_t)G*16 + (size_t)g*256;
    #pragma unroll
    for (int i = 0; i < 16; ++i) {
        // w = F_i @ NC  (F[i][k] = bq(FT[k] comp i&3, i>>2))
        v2f wlo = {0.f,0.f}, whi = {0.f,0.f};
        #pragma unroll
        for (int k = 0; k < 16; ++k) {
            const float f = bq((i&2) ? ((i&1)?FThi[k].y:FThi[k].x)
                                     : ((i&1)?FTlo[k].y:FTlo[k].x), i>>2);
            wlo += splat(f) * Plo[k];
            whi += splat(f) * Phi[k];
        }
        // out_i = w @ F^T + Q_i
        const float4 qv = qbuf[i & 1];
        if (i + 2 < 16)
            qbuf[i & 1] = *reinterpret_cast<const float4*>(Qp + (i+2)*16 + 4*l);
        v2f olo; olo.x=qv.x; olo.y=qv.y;
        v2f ohi; ohi.x=qv.z; ohi.y=qv.w;
        #pragma unroll
        for (int t = 0; t < 16; ++t) {
            const float wb = bq((t&2) ? ((t&1)?whi.y:whi.x)
                                      : ((t&1)?wlo.y:wlo.x), t>>2);
            olo += splat(wb) * FTlo[t];
            ohi += splat(wb) * FThi[t];
        }
        *reinterpret_cast<float4*>(out_pc + i*16 + 4*l) =
            make_float4(olo.x, olo.y, ohi.x, ohi.y);
    }
}

extern "C" void kernel_launch(void* const* d_in, const int* in_sizes, int n_in,
                              void* d_out, int out_size, void* d_ws, size_t ws_size,
                              hipStream_t stream) {
    const float* g_in   = (const float*)d_in[0];
    const float* g_mean = (const float*)d_in[1];
    const float* g_cov  = (const float*)d_in[2];
    const float* g_H    = (const float*)d_in[3];
    const float* g_R    = (const float*)d_in[4];
    const float* g_F    = (const float*)d_in[5];
    const float* g_Q    = (const float*)d_in[6];
    float* out = (float*)d_out;
    const int G = in_sizes[2] / 256;     // cov is [G,16,16]
    kalman_kernel<<<G/64, 256, 0, stream>>>(g_in, g_mean, g_cov, g_H, g_R, g_F, g_Q, out, G);
}

// Round 14
// 127.417 us; speedup vs baseline: 1.1802x; 1.1802x over previous
//
#include <hip/hip_runtime.h>

// Batched Kalman step: G groups, S=16, M=8, fp32.
// R14 = R12 (quad-per-group, all-register, DPP broadcasts, v2f packed math,
// FT+Q prefetched under stream-X) with:
//  - Q prefetch extended to cover ALL 16 epilogue rows: qbuf[10] preloaded
//    after the GJ solve, rows 10..15 ring-loaded during epilogue rows 0..5
//    (9-row lookahead ~1260cy > ~900cy HBM latency) -> zero epilogue Q stalls
//  - BLOCK = 64 (one wave per block, grid G/16): probes the 1-block/CU
//    residency pin seen at 10.6% occupancy for every VGPR in 132..244;
//    semantically identical (no barriers, wave-private state)
// VGPR target ~200-240: free inside the (128,256] occupancy bucket
// (R10 244 == R12 136 occupancy). NO launch_bounds min-waves (R4/R9 spills).

typedef float v2f __attribute__((ext_vector_type(2)));

__device__ __forceinline__ float bq(float x, int t) {
    // broadcast lane t of each quad (DPP quad_perm)
    switch (t & 3) {
    case 0:  return __int_as_float(__builtin_amdgcn_mov_dpp(__float_as_int(x), 0x00, 0xF, 0xF, true));
    case 1:  return __int_as_float(__builtin_amdgcn_mov_dpp(__float_as_int(x), 0x55, 0xF, 0xF, true));
    case 2:  return __int_as_float(__builtin_amdgcn_mov_dpp(__float_as_int(x), 0xAA, 0xF, 0xF, true));
    default: return __int_as_float(__builtin_amdgcn_mov_dpp(__float_as_int(x), 0xFF, 0xF, 0xF, true));
    }
}
__device__ __forceinline__ v2f splat(float c) { v2f r; r.x = c; r.y = c; return r; }

__global__ __launch_bounds__(64) void kalman_kernel(
    const float* __restrict__ g_in,
    const float* __restrict__ g_mean,
    const float* __restrict__ g_cov,
    const float* __restrict__ g_H,
    const float* __restrict__ g_R,
    const float* __restrict__ g_F,
    const float* __restrict__ g_Q,
    float* __restrict__ g_out,
    int G)
{
    const int l = threadIdx.x & 3;                         // lane in quad
    const int g = (blockIdx.x << 4) | (threadIdx.x >> 2);  // group id

    const float* const Pp = g_cov + (size_t)g * 256;
    const float* const Hp = g_H   + (size_t)g * 128;
    const float* const Rp = g_R   + (size_t)g * 64;
    const float* const Fp = g_F   + (size_t)g * 256;
    const float* const Qp = g_Q   + (size_t)g * 256;

    // ---- loads: P col-slab (cols 4l..4l+3 as 2 v2f per row) ----
    v2f Plo[16], Phi[16];
    #pragma unroll
    for (int k = 0; k < 16; ++k) {
        const float4 t = *reinterpret_cast<const float4*>(Pp + k*16 + 4*l);
        Plo[k].x=t.x; Plo[k].y=t.y; Phi[k].x=t.z; Phi[k].y=t.w;
    }
    // HT[k] = {H[2l][k], H[2l+1][k]}
    v2f HT[16];
    {
        float4 ra[4], rb[4];
        #pragma unroll
        for (int p = 0; p < 4; ++p) {
            ra[p] = *reinterpret_cast<const float4*>(Hp + (2*l  )*16 + 4*p);
            rb[p] = *reinterpret_cast<const float4*>(Hp + (2*l+1)*16 + 4*p);
        }
        #pragma unroll
        for (int p = 0; p < 4; ++p) {
            HT[4*p+0].x=ra[p].x; HT[4*p+0].y=rb[p].x;
            HT[4*p+1].x=ra[p].y; HT[4*p+1].y=rb[p].y;
            HT[4*p+2].x=ra[p].z; HT[4*p+2].y=rb[p].z;
            HT[4*p+3].x=ra[p].w; HT[4*p+3].y=rb[p].w;
        }
    }
    // S rows init R (cols 2l, 2l+1)
    v2f S[8];
    #pragma unroll
    for (int i = 0; i < 8; ++i) {
        const float2 t = *reinterpret_cast<const float2*>(Rp + i*8 + 2*l);
        S[i].x=t.x; S[i].y=t.y;
    }
    v2f mnlo, mnhi;
    { const float4 t = *reinterpret_cast<const float4*>(g_mean + (size_t)g*16 + 4*l);
      mnlo.x=t.x; mnlo.y=t.y; mnhi.x=t.z; mnhi.y=t.w; }
    v2f ipv;
    { const float2 t = *reinterpret_cast<const float2*>(g_in + (size_t)g*8 + 2*l);
      ipv.x=t.x; ipv.y=t.y; }

    // ---- CT = H@P (col-slab; H[i][k] = bq(HT[k] comp i&1, i>>1)) ----
    v2f CTlo[8], CThi[8];
    #pragma unroll
    for (int i = 0; i < 8; ++i) {
        v2f alo = {0.f, 0.f}, ahi = {0.f, 0.f};
        #pragma unroll
        for (int k = 0; k < 16; ++k) {
            const float h = bq((i&1) ? HT[k].y : HT[k].x, i>>1);
            alo += splat(h) * Plo[k];
            ahi += splat(h) * Phi[k];
        }
        CTlo[i]=alo; CThi[i]=ahi;
    }

    // ---- S = CT@H^T + R ----
    #pragma unroll
    for (int i = 0; i < 8; ++i) {
        v2f acc = S[i];
        #pragma unroll
        for (int k = 0; k < 16; ++k) {
            const float c = bq((k&2) ? ((k&1)?CThi[i].y:CThi[i].x)
                                     : ((k&1)?CTlo[i].y:CTlo[i].x), k>>2);
            acc += splat(c) * HT[k];
        }
        S[i] = acc;
    }

    // ---- res = inp - H@mean ----
    v2f resd = ipv;
    #pragma unroll
    for (int k = 0; k < 16; ++k) {
        const float m = bq((k&2) ? ((k&1)?mnhi.y:mnhi.x)
                                 : ((k&1)?mnlo.y:mnlo.x), k>>2);
        resd -= splat(m) * HT[k];
    }

    // ---- Gauss-Jordan [S | I] -> Sinv (divergence-free, in-stage pivot) ----
    v2f Ii[8];
    #pragma unroll
    for (int i = 0; i < 8; ++i) {
        Ii[i].x = (2*l   == i) ? 1.f : 0.f;
        Ii[i].y = (2*l+1 == i) ? 1.f : 0.f;
    }
    #pragma unroll
    for (int k = 0; k < 8; ++k) {
        const float pv   = bq((k&1) ? S[k].y : S[k].x, k>>1);
        const float pinv = __builtin_amdgcn_rcpf(pv);
        S[k]  *= splat(pinv);
        Ii[k] *= splat(pinv);
        #pragma unroll
        for (int i = 0; i < 8; ++i) {
            if (i == k) continue;
            const float fi = bq((k&1) ? S[i].y : S[i].x, k>>1);
            S[i]  -= splat(fi) * S[k];
            Ii[i] -= splat(fi) * Ii[k];
        }
    }
    // Ii = Sinv.

    // ==== PREFETCH: FT + first 10 Q rows issued NOW; stream-X hides them ====
    v2f FTlo[16], FThi[16];
    {
        #pragma unroll
        for (int p = 0; p < 4; ++p) {
            const float4 r0 = *reinterpret_cast<const float4*>(Fp + (4*l+0)*16 + 4*p);
            const float4 r1 = *reinterpret_cast<const float4*>(Fp + (4*l+1)*16 + 4*p);
            const float4 r2 = *reinterpret_cast<const float4*>(Fp + (4*l+2)*16 + 4*p);
            const float4 r3 = *reinterpret_cast<const float4*>(Fp + (4*l+3)*16 + 4*p);
            FTlo[4*p+0].x=r0.x; FTlo[4*p+0].y=r1.x; FThi[4*p+0].x=r2.x; FThi[4*p+0].y=r3.x;
            FTlo[4*p+1].x=r0.y; FTlo[4*p+1].y=r1.y; FThi[4*p+1].x=r2.y; FThi[4*p+1].y=r3.y;
            FTlo[4*p+2].x=r0.z; FTlo[4*p+2].y=r1.z; FThi[4*p+2].x=r2.z; FThi[4*p+2].y=r3.z;
            FTlo[4*p+3].x=r0.w; FTlo[4*p+3].y=r1.w; FThi[4*p+3].x=r2.w; FThi[4*p+3].y=r3.w;
        }
    }
    float4 qbuf[10];
    #pragma unroll
    for (int i = 0; i < 10; ++i)
        qbuf[i] = *reinterpret_cast<const float4*>(Qp + i*16 + 4*l);

    // ---- stream X rows: nm += X[m]*res ; NC(P) -= CT^T[.,m] (x) X[m] ----
    v2f nmL = mnlo, nmH = mnhi;
    #pragma unroll
    for (int m = 0; m < 8; ++m) {
        v2f xlo = {0.f,0.f}, xhi = {0.f,0.f};
        #pragma unroll
        for (int j = 0; j < 8; ++j) {
            const float s = bq((j&1) ? Ii[m].y : Ii[m].x, j>>1);
            xlo += splat(s) * CTlo[j];
            xhi += splat(s) * CThi[j];
        }
        const float r = bq((m&1) ? resd.y : resd.x, m>>1);
        nmL += splat(r) * xlo;
        nmH += splat(r) * xhi;
        #pragma unroll
        for (int s2 = 0; s2 < 16; ++s2) {
            const float c = bq((s2&2) ? ((s2&1)?CThi[m].y:CThi[m].x)
                                      : ((s2&1)?CTlo[m].y:CTlo[m].x), s2>>2);
            Plo[s2] -= splat(c) * xlo;
            Phi[s2] -= splat(c) * xhi;
        }
    }
    // P now holds NC. CT/S/Ii/HT/resd dead.

    // ---- pred_mean = F @ nm -> coalesced float4 ----
    {
        v2f plo = {0.f,0.f}, phi = {0.f,0.f};
        #pragma unroll
        for (int k = 0; k < 16; ++k) {
            const float m = bq((k&2) ? ((k&1)?nmH.y:nmH.x)
                                     : ((k&1)?nmL.y:nmL.x), k>>2);
            plo += splat(m) * FTlo[k];
            phi += splat(m) * FThi[k];
        }
        *reinterpret_cast<float4*>(g_out + (size_t)g*16 + 4*l) =
            make_float4(plo.x, plo.y, phi.x, phi.y);
    }

    // ---- pred_cov rows, fused W=F@NC then out=W@F^T+Q
    //      (qbuf[10] + ring: rows 10..15 loaded during rows 0..5;
    //       9-row lookahead ~1260cy > HBM ~900cy; compile-time indices) ----
    float* const out_pc = g_out + (size_t)G*16 + (size_t)g*256;
    #pragma unroll
    for (int i = 0; i < 16; ++i) {
        // w = F_i @ NC  (F[i][k] = bq(FT[k] comp i&3, i>>2))
        v2f wlo = {0.f,0.f}, whi = {0.f,0.f};
        #pragma unroll
        for (int k = 0; k < 16; ++k) {
            const float f = bq((i&2) ? ((i&1)?FThi[k].y:FThi[k].x)
                                     : ((i&1)?FTlo[k].y:FTlo[k].x), i>>2);
            wlo += splat(f) * Plo[k];
            whi += splat(f) * Phi[k];
        }
        // out_i = w @ F^T + Q_i
        const float4 qv = qbuf[(i < 10) ? i : (i - 10)];
        if (i < 6)
            qbuf[i] = *reinterpret_cast<const float4*>(Qp + (i+10)*16 + 4*l);
        v2f olo; olo.x=qv.x; olo.y=qv.y;
        v2f ohi; ohi.x=qv.z; ohi.y=qv.w;
        #pragma unroll
        for (int t = 0; t < 16; ++t) {
            const float wb = bq((t&2) ? ((t&1)?whi.y:whi.x)
                                      : ((t&1)?wlo.y:wlo.x), t>>2);
            olo += splat(wb) * FTlo[t];
            ohi += splat(wb) * FThi[t];
        }
        *reinterpret_cast<float4*>(out_pc + i*16 + 4*l) =
            make_float4(olo.x, olo.y, ohi.x, ohi.y);
    }
}

extern "C" void kernel_launch(void* const* d_in, const int* in_sizes, int n_in,
                              void* d_out, int out_size, void* d_ws, size_t ws_size,
                              hipStream_t stream) {
    const float* g_in   = (const float*)d_in[0];
    const float* g_mean = (const float*)d_in[1];
    const float* g_cov  = (const float*)d_in[2];
    const float* g_H    = (const float*)d_in[3];
    const float* g_R    = (const float*)d_in[4];
    const float* g_F    = (const float*)d_in[5];
    const float* g_Q    = (const float*)d_in[6];
    float* out = (float*)d_out;
    const int G = in_sizes[2] / 256;     // cov is [G,16,16]
    kalman_kernel<<<G/16, 64, 0, stream>>>(g_in, g_mean, g_cov, g_H, g_R, g_F, g_Q, out, G);
}